// Round 4
// baseline (888.380 us; speedup 1.0000x reference)
//
#include <hip/hip_runtime.h>

#define N_NODES 100000
#define N_EDGES 3200000
#define N_FEAT 24
#define PADF4 8                         // padded row = 32 floats = 128B
#define BSHIFT 8                        // 256 rows per bucket
#define NBUCK ((N_NODES + 255) >> 8)    // 391 buckets
#define EPT 16                          // edges per thread in partition
#define TILE (256 * EPT)                // 4096 edges per block-tile
#define NTILES ((N_EDGES + TILE - 1) / TILE)  // 782
#define CAP 12288                       // level-2 LDS staging entries (96KB)
#define DMAX 256                        // degree buckets for balance sort

// ---------------- small utils ----------------

__global__ void zero_kernel(int* __restrict__ p, int n) {
    int i = blockIdx.x * blockDim.x + threadIdx.x;
    if (i < n) p[i] = 0;
}

// ---------------- bucket histogram (LDS-aggregated) ----------------
__global__ __launch_bounds__(256) void bhist_kernel(const int* __restrict__ row,
                                                    int* __restrict__ bcnt) {
    __shared__ int h[NBUCK];
    for (int i = threadIdx.x; i < NBUCK; i += 256) h[i] = 0;
    __syncthreads();
    int stride = gridDim.x * blockDim.x;
    for (int i = blockIdx.x * blockDim.x + threadIdx.x; i < N_EDGES; i += stride)
        atomicAdd(&h[row[i] >> BSHIFT], 1);
    __syncthreads();
    for (int i = threadIdx.x; i < NBUCK; i += 256) {
        int c = h[i];
        if (c) atomicAdd(&bcnt[i], c);
    }
}

// ---------------- bucket exclusive scan -> bbase[0..NBUCK], bcursor ----------------
__global__ __launch_bounds__(512) void bscan_kernel(const int* __restrict__ bcnt,
                                                    int* __restrict__ bbase,
                                                    int* __restrict__ bcursor) {
    __shared__ int part[512];
    int tid = threadIdx.x;
    int v = (tid < NBUCK) ? bcnt[tid] : 0;
    part[tid] = v;
    __syncthreads();
    for (int off = 1; off < 512; off <<= 1) {
        int p = (tid >= off) ? part[tid - off] : 0;
        __syncthreads();
        part[tid] += p;
        __syncthreads();
    }
    int ex = (tid > 0) ? part[tid - 1] : 0;
    if (tid <= NBUCK) {
        bbase[tid] = ex;              // bbase[NBUCK] == N_EDGES
        if (tid < NBUCK) bcursor[tid] = ex;
    }
}

// ---------------- level 1: partition edges into bucket regions ----------------
// LDS-staged: rank edges into a bucket-sorted LDS buffer, then dump with
// lane-consecutive slots so each (block,bucket) chunk hits L2 as full sectors.
__global__ __launch_bounds__(256) void part_kernel(const int* __restrict__ row,
                                                   const int* __restrict__ col,
                                                   const float* __restrict__ val,
                                                   int* __restrict__ bcursor,
                                                   int2* __restrict__ epk) {
    __shared__ int h[NBUCK];
    __shared__ int lstart[NBUCK];
    __shared__ int delta[NBUCK];      // gpos[b] - lstart[b]
    __shared__ int psum[256];
    __shared__ int2 stage[TILE];
    __shared__ unsigned short bidx[TILE];
    const int tid = threadIdx.x;
    for (int i = tid; i < NBUCK; i += 256) h[i] = 0;
    __syncthreads();

    const int tbase = blockIdx.x * TILE;
    const int m = min(TILE, N_EDGES - tbase);   // staged count this tile
    const int base = tbase + tid * EPT;
    int rowj[EPT], rk[EPT];
    #pragma unroll
    for (int j = 0; j < EPT; ++j) {
        int e = base + j;
        if (e < N_EDGES) {
            int r = row[e];
            rowj[j] = r;
            rk[j] = atomicAdd(&h[r >> BSHIFT], 1);
        } else rowj[j] = -1;
    }
    __syncthreads();

    // exclusive scan h -> lstart (NBUCK values, 256 threads, chunk=2)
    {
        int lo = tid * 2;
        int hi = min(NBUCK, lo + 2);
        int s = 0;
        for (int j = lo; j < hi; ++j) s += h[j];
        psum[tid] = s;
        __syncthreads();
        for (int off = 1; off < 256; off <<= 1) {
            int p = (tid >= off) ? psum[tid - off] : 0;
            __syncthreads();
            psum[tid] += p;
            __syncthreads();
        }
        int run = (tid > 0) ? psum[tid - 1] : 0;
        for (int j = lo; j < hi; ++j) {
            lstart[j] = run;
            run += h[j];
        }
    }
    __syncthreads();

    // reserve global chunks
    for (int i = tid; i < NBUCK; i += 256) {
        int c = h[i];
        int g = c ? atomicAdd(&bcursor[i], c) : 0;
        delta[i] = g - lstart[i];
    }
    __syncthreads();

    // stage into bucket-sorted LDS layout
    #pragma unroll
    for (int j = 0; j < EPT; ++j) {
        if (rowj[j] >= 0) {
            int e = base + j;
            int b = rowj[j] >> BSHIFT;
            int rl = rowj[j] & 255;
            int slot = lstart[b] + rk[j];
            int2 pk;
            pk.x = col[e] | (rl << 17);   // col < 2^17, rl < 2^8
            pk.y = __float_as_int(val[e]);
            stage[slot] = pk;
            bidx[slot] = (unsigned short)b;
        }
    }
    __syncthreads();

    // dump: consecutive lanes -> consecutive slots -> contiguous chunk writes
    for (int i = tid; i < m; i += 256) {
        int b = bidx[i];
        epk[delta[b] + i] = stage[i];
    }
}

// ---------------- level 2: exact CSR placement within each bucket ----------------
__global__ __launch_bounds__(256) void place_kernel(const int* __restrict__ bbase,
                                                    int2* __restrict__ epk,
                                                    int* __restrict__ starts) {
    __shared__ int rcnt[256];
    __shared__ int rstart[256];
    __shared__ int rcur[256];
    __shared__ int2 stage[CAP];
    int b = blockIdx.x;
    int tid = threadIdx.x;
    int gb = bbase[b];
    int n = bbase[b + 1] - gb;
    rcnt[tid] = 0;
    __syncthreads();
    for (int i = tid; i < n; i += 256) {
        int rl = (epk[gb + i].x >> 17) & 255;
        atomicAdd(&rcnt[rl], 1);
    }
    __syncthreads();
    int v = rcnt[tid];
    rstart[tid] = v;
    __syncthreads();
    for (int off = 1; off < 256; off <<= 1) {
        int p = (tid >= off) ? rstart[tid - off] : 0;
        __syncthreads();
        rstart[tid] += p;
        __syncthreads();
    }
    int ex = rstart[tid] - v;
    rstart[tid] = ex;
    rcur[tid] = ex;
    __syncthreads();
    for (int i = tid; i < n; i += 256) {
        int2 p = epk[gb + i];
        int rl = (p.x >> 17) & 255;
        int slot = atomicAdd(&rcur[rl], 1);
        int2 fin;
        fin.x = p.x & 0x1FFFF;
        fin.y = p.y;
        if (slot < CAP) stage[slot] = fin;
        else epk[gb + slot] = fin;   // unreachable overflow guard
    }
    __syncthreads();
    for (int i = tid; i < n && i < CAP; i += 256) epk[gb + i] = stage[i];
    int r = (b << BSHIFT) + tid;
    if (r < N_NODES) starts[r] = gb + rstart[tid];
    if (b == 0 && tid == 0) starts[N_NODES] = N_EDGES;
}

// ---------------- degree-grouped permutation (SpMM load balance) ----------------
__global__ __launch_bounds__(256) void dhist_kernel(const int* __restrict__ starts,
                                                    int* __restrict__ dcnt) {
    int r = blockIdx.x * blockDim.x + threadIdx.x;
    if (r >= N_NODES) return;
    int d = min(starts[r + 1] - starts[r], DMAX - 1);
    atomicAdd(&dcnt[d], 1);
}

__global__ __launch_bounds__(256) void dscan_kernel(const int* __restrict__ dcnt,
                                                    int* __restrict__ dcur) {
    __shared__ int part[DMAX];
    int tid = threadIdx.x;
    int v = dcnt[tid];
    part[tid] = v;
    __syncthreads();
    for (int off = 1; off < DMAX; off <<= 1) {
        int p = (tid >= off) ? part[tid - off] : 0;
        __syncthreads();
        part[tid] += p;
        __syncthreads();
    }
    dcur[tid] = part[tid] - v;   // exclusive
}

__global__ __launch_bounds__(256) void dscatter_kernel(const int* __restrict__ starts,
                                                       int* __restrict__ dcur,
                                                       int* __restrict__ perm) {
    int r = blockIdx.x * blockDim.x + threadIdx.x;
    if (r >= N_NODES) return;
    int d = min(starts[r + 1] - starts[r], DMAX - 1);
    int p = atomicAdd(&dcur[d], 1);
    perm[p] = r;
}

// ---------------- pad-copy: x [N][24] -> bufA [N][32] ----------------
__global__ __launch_bounds__(256) void pad_copy_kernel(const float4* __restrict__ x4,
                                                       float4* __restrict__ dst) {
    int t = blockIdx.x * blockDim.x + threadIdx.x;
    int r = t >> 3;
    if (r >= N_NODES) return;
    int sub = t & 7;
    float4 v;
    if (sub < 6) v = x4[r * 6 + sub];
    else         v = make_float4(0.f, 0.f, 0.f, 0.f);
    dst[r * PADF4 + sub] = v;
}

// ---------------- SpMM on padded buffers (degree-grouped rows) ----------------
__global__ __launch_bounds__(256) void spmm_pad_kernel(const int* __restrict__ starts,
                                                       const int* __restrict__ perm,
                                                       const int2* __restrict__ epk,
                                                       const float4* __restrict__ src,
                                                       float4* __restrict__ dst) {
    int t = blockIdx.x * blockDim.x + threadIdx.x;
    int g = t >> 3;
    if (g >= N_NODES) return;
    int rowi = perm[g];
    int sub = t & 7;
    int s = starts[rowi];
    int e = starts[rowi + 1];
    float4 acc = make_float4(0.f, 0.f, 0.f, 0.f);
    for (int i = s; i < e; ++i) {
        int2 pk = epk[i];
        float v = __int_as_float(pk.y);
        float4 xv = src[pk.x * PADF4 + sub];
        acc.x = fmaf(v, xv.x, acc.x);
        acc.y = fmaf(v, xv.y, acc.y);
        acc.z = fmaf(v, xv.z, acc.z);
        acc.w = fmaf(v, xv.w, acc.w);
    }
    dst[rowi * PADF4 + sub] = acc;
}

__global__ __launch_bounds__(256) void spmm_final_kernel(const int* __restrict__ starts,
                                                         const int* __restrict__ perm,
                                                         const int2* __restrict__ epk,
                                                         const float4* __restrict__ src,
                                                         float* __restrict__ out) {
    int t = blockIdx.x * blockDim.x + threadIdx.x;
    int g = t >> 3;
    if (g >= N_NODES) return;
    int rowi = perm[g];
    int sub = t & 7;
    int s = starts[rowi];
    int e = starts[rowi + 1];
    float4 acc = make_float4(0.f, 0.f, 0.f, 0.f);
    for (int i = s; i < e; ++i) {
        int2 pk = epk[i];
        float v = __int_as_float(pk.y);
        float4 xv = src[pk.x * PADF4 + sub];
        acc.x = fmaf(v, xv.x, acc.x);
        acc.y = fmaf(v, xv.y, acc.y);
        acc.z = fmaf(v, xv.z, acc.z);
        acc.w = fmaf(v, xv.w, acc.w);
    }
    if (sub < 6) *(float4*)(out + rowi * N_FEAT + sub * 4) = acc;
}

// ---------------- launch ----------------

extern "C" void kernel_launch(void* const* d_in, const int* in_sizes, int n_in,
                              void* d_out, int out_size, void* d_ws, size_t ws_size,
                              hipStream_t stream) {
    const float* x       = (const float*)d_in[0];
    const float* values  = (const float*)d_in[1];
    const int*   row_idx = (const int*)d_in[2];
    const int*   col_idx = (const int*)d_in[3];
    float* out = (float*)d_out;

    char* ws = (char*)d_ws;
    // workspace layout (~52MB, 128B-aligned offsets)
    int*    bcnt    = (int*)(ws + 0);          // NBUCK ints
    int*    bbase   = (int*)(ws + 2048);       // NBUCK+1 ints
    int*    bcursor = (int*)(ws + 4096);       // NBUCK ints
    int*    dcnt    = (int*)(ws + 6144);       // DMAX ints
    int*    dcur    = (int*)(ws + 7168);       // DMAX ints
    int*    starts  = (int*)(ws + 8192);       // N_NODES+1 ints
    int*    perm    = (int*)(ws + 408576);     // N_NODES ints
    int2*   epk     = (int2*)(ws + 808576);    // E * 8B = 25.6 MB
    float4* bufA    = (float4*)(ws + 26408576);// N*32 floats = 12.8 MB
    float4* bufB    = (float4*)(ws + 39208576);// N*32 floats = 12.8 MB

    zero_kernel<<<4, 256, 0, stream>>>(bcnt, NBUCK);
    zero_kernel<<<1, 256, 0, stream>>>(dcnt, DMAX);
    bhist_kernel<<<512, 256, 0, stream>>>(row_idx, bcnt);
    bscan_kernel<<<1, 512, 0, stream>>>(bcnt, bbase, bcursor);
    part_kernel<<<NTILES, 256, 0, stream>>>(row_idx, col_idx, values, bcursor, epk);
    place_kernel<<<NBUCK, 256, 0, stream>>>(bbase, epk, starts);

    const int node_blocks = (N_NODES + 255) / 256;
    dhist_kernel<<<node_blocks, 256, 0, stream>>>(starts, dcnt);
    dscan_kernel<<<1, DMAX, 0, stream>>>(dcnt, dcur);
    dscatter_kernel<<<node_blocks, 256, 0, stream>>>(starts, dcur, perm);

    const int spmm_blocks = (N_NODES * 8 + 255) / 256;
    pad_copy_kernel<<<spmm_blocks, 256, 0, stream>>>((const float4*)x, bufA);
    spmm_pad_kernel<<<spmm_blocks, 256, 0, stream>>>(starts, perm, epk, bufA, bufB);
    spmm_pad_kernel<<<spmm_blocks, 256, 0, stream>>>(starts, perm, epk, bufB, bufA);
    spmm_pad_kernel<<<spmm_blocks, 256, 0, stream>>>(starts, perm, epk, bufA, bufB);
    spmm_pad_kernel<<<spmm_blocks, 256, 0, stream>>>(starts, perm, epk, bufB, bufA);
    spmm_pad_kernel<<<spmm_blocks, 256, 0, stream>>>(starts, perm, epk, bufA, bufB);
    spmm_final_kernel<<<spmm_blocks, 256, 0, stream>>>(starts, perm, epk, bufB, out);
}

// Round 5
// 536.136 us; speedup vs baseline: 1.6570x; 1.6570x over previous
//
#include <hip/hip_runtime.h>

#define N_NODES 100000
#define N_EDGES 3200000
#define N_FEAT 24
#define PADF4 8                         // padded row = 32 floats = 128B
#define BSHIFT 8                        // 256 rows per bucket
#define NBUCK ((N_NODES + 255) >> 8)    // 391 buckets
#define EPT 16                          // edges per thread in partition
#define TILE (256 * EPT)                // 4096 edges per block-tile
#define NTILES ((N_EDGES + TILE - 1) / TILE)  // 782
#define CAP 12288                       // level-2 LDS staging entries (96KB)
#define DMAX 256                        // degree buckets for balance sort

// ---------------- small utils ----------------

__global__ void zero_kernel(int* __restrict__ p, int n) {
    int i = blockIdx.x * blockDim.x + threadIdx.x;
    if (i < n) p[i] = 0;
}

// ---------------- bucket histogram (LDS-aggregated) ----------------
__global__ __launch_bounds__(256) void bhist_kernel(const int* __restrict__ row,
                                                    int* __restrict__ bcnt) {
    __shared__ int h[NBUCK];
    for (int i = threadIdx.x; i < NBUCK; i += 256) h[i] = 0;
    __syncthreads();
    int stride = gridDim.x * blockDim.x;
    for (int i = blockIdx.x * blockDim.x + threadIdx.x; i < N_EDGES; i += stride)
        atomicAdd(&h[row[i] >> BSHIFT], 1);
    __syncthreads();
    for (int i = threadIdx.x; i < NBUCK; i += 256) {
        int c = h[i];
        if (c) atomicAdd(&bcnt[i], c);
    }
}

// ---------------- bucket exclusive scan -> bbase[0..NBUCK], bcursor ----------------
__global__ __launch_bounds__(512) void bscan_kernel(const int* __restrict__ bcnt,
                                                    int* __restrict__ bbase,
                                                    int* __restrict__ bcursor) {
    __shared__ int part[512];
    int tid = threadIdx.x;
    int v = (tid < NBUCK) ? bcnt[tid] : 0;
    part[tid] = v;
    __syncthreads();
    for (int off = 1; off < 512; off <<= 1) {
        int p = (tid >= off) ? part[tid - off] : 0;
        __syncthreads();
        part[tid] += p;
        __syncthreads();
    }
    int ex = (tid > 0) ? part[tid - 1] : 0;
    if (tid <= NBUCK) {
        bbase[tid] = ex;              // bbase[NBUCK] == N_EDGES
        if (tid < NBUCK) bcursor[tid] = ex;
    }
}

// ---------------- level 1: partition edges into bucket regions ----------------
// LDS-staged: rank edges into a bucket-sorted LDS buffer, then dump with
// lane-consecutive slots so each (block,bucket) chunk hits L2 as full sectors.
__global__ __launch_bounds__(256) void part_kernel(const int* __restrict__ row,
                                                   const int* __restrict__ col,
                                                   const float* __restrict__ val,
                                                   int* __restrict__ bcursor,
                                                   int2* __restrict__ epk) {
    __shared__ int h[NBUCK];
    __shared__ int lstart[NBUCK];
    __shared__ int delta[NBUCK];      // gpos[b] - lstart[b]
    __shared__ int psum[256];
    __shared__ int2 stage[TILE];
    __shared__ unsigned short bidx[TILE];
    const int tid = threadIdx.x;
    for (int i = tid; i < NBUCK; i += 256) h[i] = 0;
    __syncthreads();

    const int tbase = blockIdx.x * TILE;
    const int m = min(TILE, N_EDGES - tbase);   // staged count this tile
    const int base = tbase + tid * EPT;
    int rowj[EPT], rk[EPT];
    #pragma unroll
    for (int j = 0; j < EPT; ++j) {
        int e = base + j;
        if (e < N_EDGES) {
            int r = row[e];
            rowj[j] = r;
            rk[j] = atomicAdd(&h[r >> BSHIFT], 1);
        } else rowj[j] = -1;
    }
    __syncthreads();

    // exclusive scan h -> lstart (NBUCK values, 256 threads, chunk=2)
    {
        int lo = tid * 2;
        int hi = min(NBUCK, lo + 2);
        int s = 0;
        for (int j = lo; j < hi; ++j) s += h[j];
        psum[tid] = s;
        __syncthreads();
        for (int off = 1; off < 256; off <<= 1) {
            int p = (tid >= off) ? psum[tid - off] : 0;
            __syncthreads();
            psum[tid] += p;
            __syncthreads();
        }
        int run = (tid > 0) ? psum[tid - 1] : 0;
        for (int j = lo; j < hi; ++j) {
            lstart[j] = run;
            run += h[j];
        }
    }
    __syncthreads();

    // reserve global chunks (one atomic per (block,bucket))
    for (int i = tid; i < NBUCK; i += 256) {
        int c = h[i];
        int g = c ? atomicAdd(&bcursor[i], c) : 0;
        delta[i] = g - lstart[i];
    }
    __syncthreads();

    // stage into bucket-sorted LDS layout
    #pragma unroll
    for (int j = 0; j < EPT; ++j) {
        if (rowj[j] >= 0) {
            int e = base + j;
            int b = rowj[j] >> BSHIFT;
            int rl = rowj[j] & 255;
            int slot = lstart[b] + rk[j];
            int2 pk;
            pk.x = col[e] | (rl << 17);   // col < 2^17, rl < 2^8
            pk.y = __float_as_int(val[e]);
            stage[slot] = pk;
            bidx[slot] = (unsigned short)b;
        }
    }
    __syncthreads();

    // dump: consecutive lanes -> consecutive slots -> contiguous chunk writes
    for (int i = tid; i < m; i += 256) {
        int b = bidx[i];
        epk[delta[b] + i] = stage[i];
    }
}

// ---------------- level 2: exact CSR placement within each bucket ----------------
// Also emits the global degree histogram (LDS-aggregated, ~64 atomics/block).
__global__ __launch_bounds__(256) void place_kernel(const int* __restrict__ bbase,
                                                    int2* __restrict__ epk,
                                                    int* __restrict__ starts,
                                                    int* __restrict__ dcnt) {
    __shared__ int rcnt[256];
    __shared__ int rstart[256];
    __shared__ int rcur[256];
    __shared__ int dh[DMAX];
    __shared__ int2 stage[CAP];
    int b = blockIdx.x;
    int tid = threadIdx.x;
    int gb = bbase[b];
    int n = bbase[b + 1] - gb;
    rcnt[tid] = 0;
    dh[tid] = 0;
    __syncthreads();
    for (int i = tid; i < n; i += 256) {
        int rl = (epk[gb + i].x >> 17) & 255;
        atomicAdd(&rcnt[rl], 1);
    }
    __syncthreads();
    int v = rcnt[tid];
    // degree histogram contribution (only for real rows)
    int r_glob = (b << BSHIFT) + tid;
    if (r_glob < N_NODES) atomicAdd(&dh[min(v, DMAX - 1)], 1);
    rstart[tid] = v;
    __syncthreads();
    for (int off = 1; off < 256; off <<= 1) {
        int p = (tid >= off) ? rstart[tid - off] : 0;
        __syncthreads();
        rstart[tid] += p;
        __syncthreads();
    }
    int ex = rstart[tid] - v;
    rstart[tid] = ex;
    rcur[tid] = ex;
    __syncthreads();
    // flush degree histogram
    {
        int c = dh[tid];
        if (c) atomicAdd(&dcnt[tid], c);
    }
    for (int i = tid; i < n; i += 256) {
        int2 p = epk[gb + i];
        int rl = (p.x >> 17) & 255;
        int slot = atomicAdd(&rcur[rl], 1);
        int2 fin;
        fin.x = p.x & 0x1FFFF;
        fin.y = p.y;
        if (slot < CAP) stage[slot] = fin;
        else epk[gb + slot] = fin;   // unreachable overflow guard
    }
    __syncthreads();
    for (int i = tid; i < n && i < CAP; i += 256) epk[gb + i] = stage[i];
    if (r_glob < N_NODES) starts[r_glob] = gb + rstart[tid];
    if (b == 0 && tid == 0) starts[N_NODES] = N_EDGES;
}

// ---------------- degree scan + LDS-aggregated counting-sort scatter ----------------
__global__ __launch_bounds__(256) void dscan_kernel(const int* __restrict__ dcnt,
                                                    int* __restrict__ dcur) {
    __shared__ int part[DMAX];
    int tid = threadIdx.x;
    int v = dcnt[tid];
    part[tid] = v;
    __syncthreads();
    for (int off = 1; off < DMAX; off <<= 1) {
        int p = (tid >= off) ? part[tid - off] : 0;
        __syncthreads();
        part[tid] += p;
        __syncthreads();
    }
    dcur[tid] = part[tid] - v;   // exclusive
}

__global__ __launch_bounds__(256) void dscatter_kernel(const int* __restrict__ starts,
                                                       int* __restrict__ dcur,
                                                       int* __restrict__ perm) {
    __shared__ int h[DMAX];
    __shared__ int chunk[DMAX];
    int tid = threadIdx.x;
    int r = blockIdx.x * 256 + tid;
    h[tid] = 0;
    __syncthreads();
    int d = -1, rk = 0;
    if (r < N_NODES) {
        d = min(starts[r + 1] - starts[r], DMAX - 1);
        rk = atomicAdd(&h[d], 1);
    }
    __syncthreads();
    int c = h[tid];
    chunk[tid] = c ? atomicAdd(&dcur[tid], c) : 0;   // one atomic per (block,deg)
    __syncthreads();
    if (r < N_NODES) perm[chunk[d] + rk] = r;
}

// ---------------- pad-copy: x [N][24] -> bufA [N][32] ----------------
__global__ __launch_bounds__(256) void pad_copy_kernel(const float4* __restrict__ x4,
                                                       float4* __restrict__ dst) {
    int t = blockIdx.x * blockDim.x + threadIdx.x;
    int r = t >> 3;
    if (r >= N_NODES) return;
    int sub = t & 7;
    float4 v;
    if (sub < 6) v = x4[r * 6 + sub];
    else         v = make_float4(0.f, 0.f, 0.f, 0.f);
    dst[r * PADF4 + sub] = v;
}

// ---------------- SpMM on padded buffers (degree-grouped rows) ----------------
__global__ __launch_bounds__(256) void spmm_pad_kernel(const int* __restrict__ starts,
                                                       const int* __restrict__ perm,
                                                       const int2* __restrict__ epk,
                                                       const float4* __restrict__ src,
                                                       float4* __restrict__ dst) {
    int t = blockIdx.x * blockDim.x + threadIdx.x;
    int g = t >> 3;
    if (g >= N_NODES) return;
    int rowi = perm[g];
    int sub = t & 7;
    int s = starts[rowi];
    int e = starts[rowi + 1];
    float4 acc = make_float4(0.f, 0.f, 0.f, 0.f);
    for (int i = s; i < e; ++i) {
        int2 pk = epk[i];
        float v = __int_as_float(pk.y);
        float4 xv = src[pk.x * PADF4 + sub];
        acc.x = fmaf(v, xv.x, acc.x);
        acc.y = fmaf(v, xv.y, acc.y);
        acc.z = fmaf(v, xv.z, acc.z);
        acc.w = fmaf(v, xv.w, acc.w);
    }
    dst[rowi * PADF4 + sub] = acc;
}

__global__ __launch_bounds__(256) void spmm_final_kernel(const int* __restrict__ starts,
                                                         const int* __restrict__ perm,
                                                         const int2* __restrict__ epk,
                                                         const float4* __restrict__ src,
                                                         float* __restrict__ out) {
    int t = blockIdx.x * blockDim.x + threadIdx.x;
    int g = t >> 3;
    if (g >= N_NODES) return;
    int rowi = perm[g];
    int sub = t & 7;
    int s = starts[rowi];
    int e = starts[rowi + 1];
    float4 acc = make_float4(0.f, 0.f, 0.f, 0.f);
    for (int i = s; i < e; ++i) {
        int2 pk = epk[i];
        float v = __int_as_float(pk.y);
        float4 xv = src[pk.x * PADF4 + sub];
        acc.x = fmaf(v, xv.x, acc.x);
        acc.y = fmaf(v, xv.y, acc.y);
        acc.z = fmaf(v, xv.z, acc.z);
        acc.w = fmaf(v, xv.w, acc.w);
    }
    if (sub < 6) *(float4*)(out + rowi * N_FEAT + sub * 4) = acc;
}

// ---------------- launch ----------------

extern "C" void kernel_launch(void* const* d_in, const int* in_sizes, int n_in,
                              void* d_out, int out_size, void* d_ws, size_t ws_size,
                              hipStream_t stream) {
    const float* x       = (const float*)d_in[0];
    const float* values  = (const float*)d_in[1];
    const int*   row_idx = (const int*)d_in[2];
    const int*   col_idx = (const int*)d_in[3];
    float* out = (float*)d_out;

    char* ws = (char*)d_ws;
    // workspace layout (~52MB, 128B-aligned offsets)
    int*    bcnt    = (int*)(ws + 0);          // NBUCK ints
    int*    bbase   = (int*)(ws + 2048);       // NBUCK+1 ints
    int*    bcursor = (int*)(ws + 4096);       // NBUCK ints
    int*    dcnt    = (int*)(ws + 6144);       // DMAX ints
    int*    dcur    = (int*)(ws + 7168);       // DMAX ints
    int*    starts  = (int*)(ws + 8192);       // N_NODES+1 ints
    int*    perm    = (int*)(ws + 408576);     // N_NODES ints
    int2*   epk     = (int2*)(ws + 808576);    // E * 8B = 25.6 MB
    float4* bufA    = (float4*)(ws + 26408576);// N*32 floats = 12.8 MB
    float4* bufB    = (float4*)(ws + 39208576);// N*32 floats = 12.8 MB

    zero_kernel<<<4, 256, 0, stream>>>(bcnt, NBUCK);
    zero_kernel<<<1, 256, 0, stream>>>(dcnt, DMAX);
    bhist_kernel<<<512, 256, 0, stream>>>(row_idx, bcnt);
    bscan_kernel<<<1, 512, 0, stream>>>(bcnt, bbase, bcursor);
    part_kernel<<<NTILES, 256, 0, stream>>>(row_idx, col_idx, values, bcursor, epk);
    place_kernel<<<NBUCK, 256, 0, stream>>>(bbase, epk, starts, dcnt);

    const int node_blocks = (N_NODES + 255) / 256;
    dscan_kernel<<<1, DMAX, 0, stream>>>(dcnt, dcur);
    dscatter_kernel<<<node_blocks, 256, 0, stream>>>(starts, dcur, perm);

    const int spmm_blocks = (N_NODES * 8 + 255) / 256;
    pad_copy_kernel<<<spmm_blocks, 256, 0, stream>>>((const float4*)x, bufA);
    spmm_pad_kernel<<<spmm_blocks, 256, 0, stream>>>(starts, perm, epk, bufA, bufB);
    spmm_pad_kernel<<<spmm_blocks, 256, 0, stream>>>(starts, perm, epk, bufB, bufA);
    spmm_pad_kernel<<<spmm_blocks, 256, 0, stream>>>(starts, perm, epk, bufA, bufB);
    spmm_pad_kernel<<<spmm_blocks, 256, 0, stream>>>(starts, perm, epk, bufB, bufA);
    spmm_pad_kernel<<<spmm_blocks, 256, 0, stream>>>(starts, perm, epk, bufA, bufB);
    spmm_final_kernel<<<spmm_blocks, 256, 0, stream>>>(starts, perm, epk, bufB, out);
}